// Round 7
// baseline (345.429 us; speedup 1.0000x reference)
//
#include <hip/hip_runtime.h>

#define N_NODES 100000
#define N_EDGES 640000
#define D       128
#define NT      ((N_NODES + 127) / 128)    // 782 row-tiles for fused kernel

#define SCAN_CHUNK  1024
#define SCAN_BLOCKS ((N_NODES + SCAN_CHUNK - 1) / SCAN_CHUNK)   // 98

// ---- d_ws layout (4B words) ----------------------------------------------
#define WS_CNT    0          // int   [100000]
#define WS_OFFS   100000     // int   [100000]
#define WS_CURSOR 200000     // int   [100000]
#define WS_COL    300000     // int   [640000]
#define WS_BSUM   940000     // int   [1024]
#define WS_BIAS   941056     // f32   [128]
#define WS_WT     941184     // bf16  [32768] = 16384 words (pre-swizzled W^T)
// total ≈ 3.83 MB

// RNE float->bf16 (finite inputs only)
__device__ __forceinline__ unsigned short f2bf(float f) {
    union { float f; unsigned u; } c; c.f = f;
    unsigned r = c.u + 0x7fffu + ((c.u >> 16) & 1u);
    return (unsigned short)(r >> 16);
}

// ---------------------------------------------------------------------------
// prep (merged with cnt zeroing): Wt_swz + bias_sum + cnt=0
// Wt content: Wt[n][k] = Wcat[k][n], Wcat = [W_self ; W_neigh] (256 x 128).
// Global byte n*512 + (((k>>3) ^ (n&15))*16) + (k&7)*2 holds Wcat[k][n].
// Fused kernel copies this linearly to LDS, reads frags with the same XOR
// (rule #21: swizzle source + read, keep the LDS copy linear).
// ---------------------------------------------------------------------------
__global__ __launch_bounds__(256) void k_prepw(
    const float* __restrict__ Wself, const float* __restrict__ Wneigh,
    const float* __restrict__ bself, const float* __restrict__ bneigh,
    unsigned short* wt, float* bias, int* cnt)
{
    int i = blockIdx.x * 256 + threadIdx.x;       // grid 391 -> 100096 threads
    if (i < 32768) {
        int k = i >> 7, n = i & 127;
        float v = (k < 128) ? Wself[k * 128 + n] : Wneigh[(k - 128) * 128 + n];
        int byte = n * 512 + (((k >> 3) ^ (n & 15)) << 4) + ((k & 7) << 1);
        *(unsigned short*)((char*)wt + byte) = f2bf(v);
    }
    if (i < N_NODES) cnt[i] = 0;
    if (blockIdx.x == 0 && threadIdx.x < 128)
        bias[threadIdx.x] = bself[threadIdx.x] + bneigh[threadIdx.x];
}

// ---------------------------------------------------------------------------
// 1) histogram: cnt[dst]++
// ---------------------------------------------------------------------------
__global__ __launch_bounds__(256) void k_hist(const int* __restrict__ ei, int* cnt)
{
    int e = blockIdx.x * 256 + threadIdx.x;          // grid sized exactly
    atomicAdd(&cnt[ei[N_EDGES + e]], 1);
}

// ---------------------------------------------------------------------------
// 2) two-level exclusive scan of cnt -> offs
// ---------------------------------------------------------------------------
__global__ __launch_bounds__(SCAN_CHUNK) void k_scan_a(
    const int* __restrict__ cnt, int* offs, int* bsum)
{
    __shared__ int s[SCAN_CHUNK];
    int t = threadIdx.x, b = blockIdx.x;
    int i = b * SCAN_CHUNK + t;
    int v = (i < N_NODES) ? cnt[i] : 0;
    s[t] = v;
    __syncthreads();
    for (int off = 1; off < SCAN_CHUNK; off <<= 1) {
        int u = s[t];
        int w = (t >= off) ? s[t - off] : 0;
        __syncthreads();
        s[t] = u + w;
        __syncthreads();
    }
    if (i < N_NODES) offs[i] = s[t] - v;
    if (t == SCAN_CHUNK - 1) bsum[b] = s[t];
}

__global__ __launch_bounds__(128) void k_scan_b(int* bsum)
{
    __shared__ int s[128];
    int t = threadIdx.x;
    if (t < SCAN_BLOCKS) s[t] = bsum[t];
    __syncthreads();
    if (t == 0) {
        int run = 0;
        for (int j = 0; j < SCAN_BLOCKS; ++j) { int tmp = s[j]; s[j] = run; run += tmp; }
    }
    __syncthreads();
    if (t < SCAN_BLOCKS) bsum[t] = s[t];
}

__global__ __launch_bounds__(SCAN_CHUNK) void k_scan_c(
    int* offs, int* cursor, const int* __restrict__ bsum)
{
    int i = blockIdx.x * SCAN_CHUNK + threadIdx.x;
    if (i < N_NODES) {
        int o = offs[i] + bsum[blockIdx.x];
        offs[i] = o;
        cursor[i] = o;
    }
}

// ---------------------------------------------------------------------------
// 3) bucket edges: col[pos] = src, grouped by dst
// ---------------------------------------------------------------------------
__global__ __launch_bounds__(256) void k_scatter(
    const int* __restrict__ ei, int* cursor, int* col)
{
    int e = blockIdx.x * 256 + threadIdx.x;
    int src = ei[e];
    int dst = ei[N_EDGES + e];
    int pos = atomicAdd(&cursor[dst], 1);
    col[pos] = src;
}

// ---------------------------------------------------------------------------
// 4) FUSED gather+GEMM: out[r] = [x[r] | mean[r]] @ Wcat + bias
//    - 128-row tile/block, 4 waves, 256 threads, LDS 128KB (A 64K + W 64K)
//    - phase 0: stage W (linear copy of pre-swizzled wt)
//    - phase 1: stage A x-half (global f32 -> bf16, XOR-swizzled ds_write)
//    - phase 2: gather means straight into A mean-half LDS (never global!)
//        2 nodes per wave pass (32-lane groups, float4/lane), 2-deep edge
//        pipeline -> ~16 rows in flight per CU (BW-delay ~5KB needed)
//    - one barrier (cross-wave data = W only; A rows are wave-private)
//    - MFMA 16x16x32 bf16, acc[2][8] f32x4; epilogue adds bias
//    - d_out is WRITE-ONLY (no in-place hazard)
//    A swizzle: byte(r,k) = r*512 + (((k>>3) ^ (r&15))<<4) + (k&7)*2
// ---------------------------------------------------------------------------
typedef __attribute__((ext_vector_type(8))) short bf16x8;
typedef __attribute__((ext_vector_type(4))) float f32x4;

extern __shared__ char ldsb[];

__global__ __launch_bounds__(256) void k_fused(
    const float* __restrict__ x,
    const unsigned short* __restrict__ wt,
    const float* __restrict__ bias,
    const int* __restrict__ offs, const int* __restrict__ cnt,
    const int* __restrict__ col,
    float* __restrict__ outp)
{
    char* ldsA = ldsb;               // 65536 B
    char* ldsW = ldsb + 65536;       // 65536 B

    const int w = threadIdx.x >> 6, l = threadIdx.x & 63;
    const int r0 = blockIdx.x * 128;

    // ---- phase 0: stage W (content already swizzled, linear 16B copies) ----
    {
        const uint4* wt4 = (const uint4*)wt;          // 4096 x 16B
        #pragma unroll
        for (int it = 0; it < 16; ++it) {
            int q = (w * 16 + it) * 64 + l;
            *(uint4*)(ldsW + (size_t)q * 16) = wt4[q];
        }
    }

    // ---- phase 1: stage A x-half (rows w*32 .. w*32+31) ----
    {
        const float4* xf = (const float4*)x;
        float4 vx[16];
        #pragma unroll
        for (int it = 0; it < 16; ++it) {
            int rl = 2 * it + (l >> 5);                       // 0..31
            int rg = min(r0 + w * 32 + rl, N_NODES - 1);      // clamp tail
            int j  = l & 31;
            vx[it] = xf[(size_t)rg * 32 + j];
        }
        #pragma unroll
        for (int it = 0; it < 16; ++it) {
            int rloc = w * 32 + 2 * it + (l >> 5);
            int j    = l & 31;
            int unit = (j >> 1) ^ (rloc & 15);                // k = j*4..j*4+3
            ushort4 b;
            b.x = f2bf(vx[it].x); b.y = f2bf(vx[it].y);
            b.z = f2bf(vx[it].z); b.w = f2bf(vx[it].w);
            *(ushort4*)(ldsA + rloc * 512 + (unit << 4) + ((j & 1) << 3)) = b;
        }
    }

    // ---- phase 2: gather means into A mean-half ----
    {
        const int g  = l >> 5;            // 32-lane group 0/1
        const int lg = l & 31;
        #pragma unroll 1
        for (int i = 0; i < 16; ++i) {
            int rloc  = w * 32 + 2 * i + g;
            int node  = min(r0 + rloc, N_NODES - 1);
            int start = offs[node];
            int deg   = cnt[node];

            float4 acc = {0.f, 0.f, 0.f, 0.f};
            for (int base = 0; base < deg; base += 32) {
                int c = (base + lg < deg) ? col[start + base + lg] : 0;
                int m = min(deg - base, 32);
                int j = 0;
                for (; j + 2 <= m; j += 2) {
                    int s0 = __shfl(c, j, 32);
                    int s1 = __shfl(c, j + 1, 32);
                    float4 a = ((const float4*)(x + (size_t)s0 * D))[lg];
                    float4 b = ((const float4*)(x + (size_t)s1 * D))[lg];
                    acc.x += a.x + b.x;  acc.y += a.y + b.y;
                    acc.z += a.z + b.z;  acc.w += a.w + b.w;
                }
                if (j < m) {
                    int s0 = __shfl(c, j, 32);
                    float4 a = ((const float4*)(x + (size_t)s0 * D))[lg];
                    acc.x += a.x;  acc.y += a.y;
                    acc.z += a.z;  acc.w += a.w;
                }
            }
            float inv = 1.0f / fmaxf((float)deg, 1.0f);
            // mean-half: k = 4*lg..4*lg+3 -> unit16 = 16 + (lg>>1)
            int unit = (16 + (lg >> 1)) ^ (rloc & 15);
            ushort4 b;
            b.x = f2bf(acc.x * inv); b.y = f2bf(acc.y * inv);
            b.z = f2bf(acc.z * inv); b.w = f2bf(acc.w * inv);
            *(ushort4*)(ldsA + rloc * 512 + (unit << 4) + ((lg & 1) << 3)) = b;
        }
    }
    __syncthreads();

    // ---- MFMA K-loop ----
    const int ln = l & 15, kq = l >> 4;
    const int rA0 = w * 32 + ln;          // rg=0 local row; rA0&15 == ln
    const int rA1 = rA0 + 16;             // rg=1

    f32x4 acc[2][8];
    #pragma unroll
    for (int rg = 0; rg < 2; ++rg)
        #pragma unroll
        for (int cg = 0; cg < 8; ++cg)
            acc[rg][cg] = (f32x4){0.f, 0.f, 0.f, 0.f};

    #pragma unroll
    for (int ks = 0; ks < 8; ++ks) {
        int i = ks * 4 + kq;              // 16B-unit index 0..31
        bf16x8 a0 = *(const bf16x8*)(ldsA + rA0 * 512 + ((i ^ ln) << 4));
        bf16x8 a1 = *(const bf16x8*)(ldsA + rA1 * 512 + ((i ^ ln) << 4));
        #pragma unroll
        for (int cg = 0; cg < 8; ++cg) {
            int n = cg * 16 + ln;
            bf16x8 bfr = *(const bf16x8*)(ldsW + n * 512 + ((i ^ ln) << 4));
            acc[0][cg] = __builtin_amdgcn_mfma_f32_16x16x32_bf16(a0, bfr, acc[0][cg], 0, 0, 0);
            acc[1][cg] = __builtin_amdgcn_mfma_f32_16x16x32_bf16(a1, bfr, acc[1][cg], 0, 0, 0);
        }
    }

    // ---- epilogue: C/D layout col=ln, row=kq*4+q (m89-verified) ----
    float bv[8];
    #pragma unroll
    for (int cg = 0; cg < 8; ++cg) bv[cg] = bias[cg * 16 + ln];

    #pragma unroll
    for (int rg = 0; rg < 2; ++rg) {
        int rbase = r0 + w * 32 + rg * 16 + kq * 4;
        #pragma unroll
        for (int q = 0; q < 4; ++q) {
            int rr = rbase + q;
            if (rr < N_NODES) {
                float* op = outp + (size_t)rr * D + ln;
                #pragma unroll
                for (int cg = 0; cg < 8; ++cg)
                    op[cg * 16] = acc[rg][cg][q] + bv[cg];
            }
        }
    }
}

// ---------------------------------------------------------------------------
extern "C" void kernel_launch(void* const* d_in, const int* in_sizes, int n_in,
                              void* d_out, int out_size, void* d_ws, size_t ws_size,
                              hipStream_t stream) {
    const float* x      = (const float*)d_in[0];
    const int*   ei     = (const int*)  d_in[1];   // harness delivers int32
    const float* Wself  = (const float*)d_in[2];
    const float* bself  = (const float*)d_in[3];
    const float* Wneigh = (const float*)d_in[4];
    const float* bneigh = (const float*)d_in[5];

    float* out = (float*)d_out;
    int*   ws  = (int*)d_ws;
    int* cnt    = ws + WS_CNT;
    int* offs   = ws + WS_OFFS;
    int* cursor = ws + WS_CURSOR;
    int* col    = ws + WS_COL;
    int* bsum   = ws + WS_BSUM;
    float* bias = (float*)(ws + WS_BIAS);
    unsigned short* wt = (unsigned short*)(ws + WS_WT);

    k_prepw  <<<391, 256, 0, stream>>>(Wself, Wneigh, bself, bneigh, wt, bias, cnt);
    k_hist   <<<N_EDGES / 256, 256, 0, stream>>>(ei, cnt);
    k_scan_a <<<SCAN_BLOCKS, SCAN_CHUNK, 0, stream>>>(cnt, offs, bsum);
    k_scan_b <<<1, 128, 0, stream>>>(bsum);
    k_scan_c <<<SCAN_BLOCKS, SCAN_CHUNK, 0, stream>>>(offs, cursor, bsum);
    k_scatter<<<N_EDGES / 256, 256, 0, stream>>>(ei, cursor, col);

    size_t lds_bytes = 131072;
    hipFuncSetAttribute((const void*)k_fused,
                        hipFuncAttributeMaxDynamicSharedMemorySize, (int)lds_bytes);
    k_fused<<<NT, 256, lds_bytes, stream>>>(x, wt, bias, offs, cnt, col, out);
}

// Round 8
// 226.728 us; speedup vs baseline: 1.5235x; 1.5235x over previous
//
#include <hip/hip_runtime.h>

#define N_NODES 100000
#define N_EDGES 640000
#define D       128
#define NT      ((N_NODES + 127) / 128)    // 782 row-tiles for gemm
#define SLOTS   16
#define SPILL_CAP 65536

#define SCAN_CHUNK  1024
#define SCAN_BLOCKS ((N_NODES + SCAN_CHUNK - 1) / SCAN_CHUNK)   // 98

// ---- PATH A ws layout (4B words), needs ~7.39 MB -------------------------
#define A_CNT   0          // int [100001]  (index 100000 = spill counter)
#define A_COL   100002     // int [1600000] (16 slots/node)
#define A_SPILL 1700002    // int2[65536]   (word idx even -> 8B aligned)
#define A_BIAS  1831074    // f32 [128]
#define A_WT    1831204    // bf16[32768] = 16384 words (16B aligned: 1831204%4==0)
#define A_TOTAL 1847588    // words

// ---- PATH B ws layout (round-6 verified fallback), 3.83 MB ---------------
#define WS_CNT    0
#define WS_OFFS   100000
#define WS_CURSOR 200000
#define WS_COL    300000
#define WS_BSUM   940000
#define WS_BIAS   941056
#define WS_WT     941184

// RNE float->bf16 (finite inputs only)
__device__ __forceinline__ unsigned short f2bf(float f) {
    union { float f; unsigned u; } c; c.f = f;
    unsigned r = c.u + 0x7fffu + ((c.u >> 16) & 1u);
    return (unsigned short)(r >> 16);
}

// ---------------------------------------------------------------------------
// prep: Wt_swz + bias_sum + zero cnt[0..n_zero)
// Wt content: Wt[n][k] = Wcat[k][n], Wcat = [W_self ; W_neigh] (256 x 128).
// Global byte n*512 + (((k>>3) ^ (n&15))*16) + (k&7)*2 holds Wcat[k][n]
// (rule #21: swizzled source + swizzled read, linear LDS copy).
// ---------------------------------------------------------------------------
__global__ __launch_bounds__(256) void k_prepw(
    const float* __restrict__ Wself, const float* __restrict__ Wneigh,
    const float* __restrict__ bself, const float* __restrict__ bneigh,
    unsigned short* wt, float* bias, int* cnt, int n_zero)
{
    int i = blockIdx.x * 256 + threadIdx.x;       // grid 391 -> 100096 threads
    if (i < 32768) {
        int k = i >> 7, n = i & 127;
        float v = (k < 128) ? Wself[k * 128 + n] : Wneigh[(k - 128) * 128 + n];
        int byte = n * 512 + (((k >> 3) ^ (n & 15)) << 4) + ((k & 7) << 1);
        *(unsigned short*)((char*)wt + byte) = f2bf(v);
    }
    if (i < n_zero) cnt[i] = 0;
    if (blockIdx.x == 0 && threadIdx.x < 128)
        bias[threadIdx.x] = bself[threadIdx.x] + bneigh[threadIdx.x];
}

// ===========================================================================
// PATH A: one-kernel adjacency build (fixed 16 slots + spill pool)
// ===========================================================================
__global__ __launch_bounds__(256) void k_scat16(
    const int* __restrict__ ei, int* cnt, int* col16, int2* spill)
{
    int e = blockIdx.x * 256 + threadIdx.x;
    int src = ei[e];
    int dst = ei[N_EDGES + e];
    int pos = atomicAdd(&cnt[dst], 1);       // histogram AND cursor
    if (pos < SLOTS) {
        col16[dst * SLOTS + pos] = src;
    } else {
        int j = atomicAdd(&cnt[N_NODES], 1);
        if (j < SPILL_CAP) spill[j] = make_int2(dst, src);
    }
}

// gather MEAN (fp32) into d_out. One wave per node; <=16 inline neighbors
// (one col load per lane), rare deg>16 nodes scan the spill pool.
__global__ __launch_bounds__(256) void k_gather16(
    const float* __restrict__ x, const int* __restrict__ cnt,
    const int* __restrict__ col16, const int2* __restrict__ spill,
    float* out)
{
    int node = blockIdx.x * 4 + (threadIdx.x >> 6);      // grid 25000 exact
    int l = threadIdx.x & 63;
    int deg = cnt[node];
    int m = min(deg, SLOTS);
    int c = (l < m) ? col16[node * SLOTS + l] : 0;

    float2 acc = make_float2(0.f, 0.f);
    int j = 0;
    for (; j + 2 <= m; j += 2) {
        int s0 = __shfl(c, j);
        int s1 = __shfl(c, j + 1);
        float2 a = ((const float2*)(x + (size_t)s0 * D))[l];
        float2 b = ((const float2*)(x + (size_t)s1 * D))[l];
        acc.x += a.x + b.x;
        acc.y += a.y + b.y;
    }
    if (j < m) {
        int s0 = __shfl(c, j);
        float2 a = ((const float2*)(x + (size_t)s0 * D))[l];
        acc.x += a.x;
        acc.y += a.y;
    }
    if (deg > SLOTS) {                        // ~10 nodes expected
        int tot = min(cnt[N_NODES], SPILL_CAP);
        for (int i = 0; i < tot; ++i) {
            int2 p = spill[i];
            if (p.x == node) {
                float2 a = ((const float2*)(x + (size_t)p.y * D))[l];
                acc.x += a.x;
                acc.y += a.y;
            }
        }
    }
    float inv = 1.0f / fmaxf((float)deg, 1.0f);
    ((float2*)(out + (size_t)node * D))[l] = make_float2(acc.x * inv, acc.y * inv);
}

// ===========================================================================
// PATH B: round-6 verified CSR chain (fallback if ws_size < 7.5 MB)
// ===========================================================================
__global__ __launch_bounds__(256) void k_hist(const int* __restrict__ ei, int* cnt)
{
    int e = blockIdx.x * 256 + threadIdx.x;
    atomicAdd(&cnt[ei[N_EDGES + e]], 1);
}

__global__ __launch_bounds__(SCAN_CHUNK) void k_scan_a(
    const int* __restrict__ cnt, int* offs, int* bsum)
{
    __shared__ int s[SCAN_CHUNK];
    int t = threadIdx.x, b = blockIdx.x;
    int i = b * SCAN_CHUNK + t;
    int v = (i < N_NODES) ? cnt[i] : 0;
    s[t] = v;
    __syncthreads();
    for (int off = 1; off < SCAN_CHUNK; off <<= 1) {
        int u = s[t];
        int w = (t >= off) ? s[t - off] : 0;
        __syncthreads();
        s[t] = u + w;
        __syncthreads();
    }
    if (i < N_NODES) offs[i] = s[t] - v;
    if (t == SCAN_CHUNK - 1) bsum[b] = s[t];
}

__global__ __launch_bounds__(128) void k_scan_b(int* bsum)
{
    __shared__ int s[128];
    int t = threadIdx.x;
    if (t < SCAN_BLOCKS) s[t] = bsum[t];
    __syncthreads();
    if (t == 0) {
        int run = 0;
        for (int j = 0; j < SCAN_BLOCKS; ++j) { int tmp = s[j]; s[j] = run; run += tmp; }
    }
    __syncthreads();
    if (t < SCAN_BLOCKS) bsum[t] = s[t];
}

__global__ __launch_bounds__(SCAN_CHUNK) void k_scan_c(
    int* offs, int* cursor, const int* __restrict__ bsum)
{
    int i = blockIdx.x * SCAN_CHUNK + threadIdx.x;
    if (i < N_NODES) {
        int o = offs[i] + bsum[blockIdx.x];
        offs[i] = o;
        cursor[i] = o;
    }
}

__global__ __launch_bounds__(256) void k_scatter(
    const int* __restrict__ ei, int* cursor, int* col)
{
    int e = blockIdx.x * 256 + threadIdx.x;
    int src = ei[e];
    int dst = ei[N_EDGES + e];
    int pos = atomicAdd(&cursor[dst], 1);
    col[pos] = src;
}

__global__ __launch_bounds__(256) void k_gather(
    const float* __restrict__ x, const int* __restrict__ offs,
    const int* __restrict__ cnt, const int* __restrict__ col,
    float* out)
{
    int node = blockIdx.x * 4 + (threadIdx.x >> 6);
    int l = threadIdx.x & 63;
    int start = offs[node];
    int deg   = cnt[node];

    float2 acc = make_float2(0.f, 0.f);
    for (int base = 0; base < deg; base += 64) {
        int idx = base + l;
        int c = (idx < deg) ? col[start + idx] : 0;
        int m = min(deg - base, 64);
        int j = 0;
        for (; j + 2 <= m; j += 2) {
            int s0 = __shfl(c, j);
            int s1 = __shfl(c, j + 1);
            float2 a = ((const float2*)(x + (size_t)s0 * D))[l];
            float2 b = ((const float2*)(x + (size_t)s1 * D))[l];
            acc.x += a.x + b.x;
            acc.y += a.y + b.y;
        }
        if (j < m) {
            int s0 = __shfl(c, j);
            float2 a = ((const float2*)(x + (size_t)s0 * D))[l];
            acc.x += a.x;
            acc.y += a.y;
        }
    }
    float inv = 1.0f / fmaxf((float)deg, 1.0f);
    ((float2*)(out + (size_t)node * D))[l] = make_float2(acc.x * inv, acc.y * inv);
}

// ===========================================================================
// MFMA GEMM (shared): out[r] = [x[r] | mean[r]] @ Wcat + bias
// (round-6 verified: 128-row tile, 4 waves, A+W in 128KB LDS, XOR-swizzled,
//  in-place mean read on d_out drains to regs before the barrier)
// A swizzle: byte(r,k) = r*512 + (((k>>3) ^ (r&15))<<4) + (k&7)*2
// ===========================================================================
typedef __attribute__((ext_vector_type(8))) short bf16x8;
typedef __attribute__((ext_vector_type(4))) float f32x4;

extern __shared__ char ldsb[];

__global__ __launch_bounds__(256) void k_gemm(
    const float* __restrict__ x,
    const unsigned short* __restrict__ wt,
    const float* __restrict__ bias,
    float* outp)
{
    char* ldsA = ldsb;               // 65536 B
    char* ldsW = ldsb + 65536;       // 65536 B

    const int w = threadIdx.x >> 6, l = threadIdx.x & 63;
    const int r0 = blockIdx.x * 128;

    {   // stage W: linear 16B copies (content already swizzled)
        const uint4* wt4 = (const uint4*)wt;          // 4096 x 16B
        #pragma unroll
        for (int it = 0; it < 16; ++it) {
            int q = (w * 16 + it) * 64 + l;
            *(uint4*)(ldsW + (size_t)q * 16) = wt4[q];
        }
    }

    {   // stage A: 32 rows per wave; halves: 0=x, 1=mean(d_out)
        const float4* xf = (const float4*)x;
        const float4* mf = (const float4*)outp;
        float4 vx[16], vm[16];
        #pragma unroll
        for (int it = 0; it < 16; ++it) {
            int rl = 2 * it + (l >> 5);
            int rg = min(r0 + w * 32 + rl, N_NODES - 1);      // clamp tail
            int j  = l & 31;
            vx[it] = xf[(size_t)rg * 32 + j];
            vm[it] = mf[(size_t)rg * 32 + j];
        }
        #pragma unroll
        for (int it = 0; it < 16; ++it) {
            int rloc = w * 32 + 2 * it + (l >> 5);
            int j    = l & 31;
            {
                int unit = ((j >> 1) ^ (rloc & 15));
                ushort4 b;
                b.x = f2bf(vx[it].x); b.y = f2bf(vx[it].y);
                b.z = f2bf(vx[it].z); b.w = f2bf(vx[it].w);
                *(ushort4*)(ldsA + rloc * 512 + (unit << 4) + ((j & 1) << 3)) = b;
            }
            {
                int unit = ((16 + (j >> 1)) ^ (rloc & 15));
                ushort4 b;
                b.x = f2bf(vm[it].x); b.y = f2bf(vm[it].y);
                b.z = f2bf(vm[it].z); b.w = f2bf(vm[it].w);
                *(ushort4*)(ldsA + rloc * 512 + (unit << 4) + ((j & 1) << 3)) = b;
            }
        }
    }
    __syncthreads();

    const int ln = l & 15, kq = l >> 4;
    const int rA0 = w * 32 + ln;
    const int rA1 = rA0 + 16;

    f32x4 acc[2][8];
    #pragma unroll
    for (int rg = 0; rg < 2; ++rg)
        #pragma unroll
        for (int cg = 0; cg < 8; ++cg)
            acc[rg][cg] = (f32x4){0.f, 0.f, 0.f, 0.f};

    #pragma unroll
    for (int ks = 0; ks < 8; ++ks) {
        int i = ks * 4 + kq;
        bf16x8 a0 = *(const bf16x8*)(ldsA + rA0 * 512 + ((i ^ ln) << 4));
        bf16x8 a1 = *(const bf16x8*)(ldsA + rA1 * 512 + ((i ^ ln) << 4));
        #pragma unroll
        for (int cg = 0; cg < 8; ++cg) {
            int n = cg * 16 + ln;
            bf16x8 bfr = *(const bf16x8*)(ldsW + n * 512 + ((i ^ ln) << 4));
            acc[0][cg] = __builtin_amdgcn_mfma_f32_16x16x32_bf16(a0, bfr, acc[0][cg], 0, 0, 0);
            acc[1][cg] = __builtin_amdgcn_mfma_f32_16x16x32_bf16(a1, bfr, acc[1][cg], 0, 0, 0);
        }
    }

    float bv[8];
    #pragma unroll
    for (int cg = 0; cg < 8; ++cg) bv[cg] = bias[cg * 16 + ln];

    #pragma unroll
    for (int rg = 0; rg < 2; ++rg) {
        int rbase = r0 + w * 32 + rg * 16 + kq * 4;
        #pragma unroll
        for (int q = 0; q < 4; ++q) {
            int rr = rbase + q;
            if (rr < N_NODES) {
                float* op = outp + (size_t)rr * D + ln;
                #pragma unroll
                for (int cg = 0; cg < 8; ++cg)
                    op[cg * 16] = acc[rg][cg][q] + bv[cg];
            }
        }
    }
}

// ---------------------------------------------------------------------------
extern "C" void kernel_launch(void* const* d_in, const int* in_sizes, int n_in,
                              void* d_out, int out_size, void* d_ws, size_t ws_size,
                              hipStream_t stream) {
    const float* x      = (const float*)d_in[0];
    const int*   ei     = (const int*)  d_in[1];
    const float* Wself  = (const float*)d_in[2];
    const float* bself  = (const float*)d_in[3];
    const float* Wneigh = (const float*)d_in[4];
    const float* bneigh = (const float*)d_in[5];

    float* out = (float*)d_out;
    int*   ws  = (int*)d_ws;
    size_t lds_bytes = 131072;
    hipFuncSetAttribute((const void*)k_gemm,
                        hipFuncAttributeMaxDynamicSharedMemorySize, (int)lds_bytes);

    if (ws_size >= (size_t)A_TOTAL * 4 + 65536) {
        // ---- PATH A: 4 dispatches ----
        int*  cnt   = ws + A_CNT;
        int*  col16 = ws + A_COL;
        int2* spill = (int2*)(ws + A_SPILL);
        float* bias = (float*)(ws + A_BIAS);
        unsigned short* wt = (unsigned short*)(ws + A_WT);

        k_prepw   <<<391, 256, 0, stream>>>(Wself, Wneigh, bself, bneigh,
                                            wt, bias, cnt, N_NODES + 1);
        k_scat16  <<<N_EDGES / 256, 256, 0, stream>>>(ei, cnt, col16, spill);
        k_gather16<<<N_NODES / 4, 256, 0, stream>>>(x, cnt, col16, spill, out);
        k_gemm    <<<NT, 256, lds_bytes, stream>>>(x, wt, bias, out);
    } else {
        // ---- PATH B: verified round-6 CSR chain ----
        int* cnt    = ws + WS_CNT;
        int* offs   = ws + WS_OFFS;
        int* cursor = ws + WS_CURSOR;
        int* col    = ws + WS_COL;
        int* bsum   = ws + WS_BSUM;
        float* bias = (float*)(ws + WS_BIAS);
        unsigned short* wt = (unsigned short*)(ws + WS_WT);

        k_prepw  <<<391, 256, 0, stream>>>(Wself, Wneigh, bself, bneigh,
                                           wt, bias, cnt, N_NODES);
        k_hist   <<<N_EDGES / 256, 256, 0, stream>>>(ei, cnt);
        k_scan_a <<<SCAN_BLOCKS, SCAN_CHUNK, 0, stream>>>(cnt, offs, bsum);
        k_scan_b <<<1, 128, 0, stream>>>(bsum);
        k_scan_c <<<SCAN_BLOCKS, SCAN_CHUNK, 0, stream>>>(offs, cursor, bsum);
        k_scatter<<<N_EDGES / 256, 256, 0, stream>>>(ei, cursor, col);
        k_gather <<<N_NODES / 4, 256, 0, stream>>>(x, offs, cnt, col, out);
        k_gemm   <<<NT, 256, lds_bytes, stream>>>(x, wt, bias, out);
    }
}